// Round 2
// baseline (333.301 us; speedup 1.0000x reference)
//
#include <hip/hip_runtime.h>
#include <hip/hip_bf16.h>
#include <math.h>

// EquivariantGraphConv fused kernel for MI355X (gfx950).
// B=2, N=512, D=HID=OUT=128.
//
// Key algebraic factorization: edge pre-activation
//   h1[i,j,:] = (feat_i @ eW1[0:128] + eb1) + (feat_j @ eW1[128:256]) + dist_ij * eW1[256]
// The i-part (Abuf, with eb1 folded) and j-part (Bbuf) are precomputed per node,
// removing the 257-wide GEMM entirely. Remaining heavy work: two 128x128 GEMMs
// per edge tile (eW2 and cW1), done with bf16 MFMA, f32 accumulate.
//
// (Resubmission of round-1 kernel: previous bench failed on container
// acquisition, no kernel-side signal.)

typedef float f32x4 __attribute__((ext_vector_type(4)));
typedef short short8 __attribute__((ext_vector_type(8)));

#define MFMA16(a, b, c) __builtin_amdgcn_mfma_f32_16x16x32_bf16((a), (b), (c), 0, 0, 0)

__device__ __forceinline__ short f2bf(float x) {
    union { float f; unsigned u; } v; v.f = x;
    unsigned r = v.u + 0x7FFFu + ((v.u >> 16) & 1u);  // RNE
    return (short)(r >> 16);
}

__device__ __forceinline__ float silu_f(float x) {
    return x * __builtin_amdgcn_rcpf(1.0f + __expf(-x));
}

// XOR swizzle for [rows][128] bf16 LDS tiles: permutes 16B chunks within each
// 128B row-window so that column-slice ds_read_b128 across rows is ~conflict-free
// (G4: row-major stride-256B is otherwise a 32-way conflict).
__device__ __forceinline__ int swz(int row, int col) {
    int byte = (row << 8) | (col << 1);
    byte ^= (row & 7) << 4;
    return byte >> 1;  // bf16-element index
}

// ---------- precompute: Abuf = feat @ eW1[0:128] + eb1 ; Bbuf = feat @ eW1[128:256]
__global__ void egnn_pre(const float* __restrict__ feat, const float* __restrict__ eW1,
                         const float* __restrict__ eb1,
                         float* __restrict__ Abuf, float* __restrict__ Bbuf) {
    __shared__ float f[128];
    const int nid = blockIdx.x;  // b*512 + i
    const int t = threadIdx.x;   // 128 threads
    f[t] = feat[nid * 128 + t];
    __syncthreads();
    float a = eb1[t], bb = 0.f;
    #pragma unroll 4
    for (int k = 0; k < 128; ++k) {
        float fv = f[k];
        a  += fv * eW1[k * 128 + t];          // coalesced across t
        bb += fv * eW1[(128 + k) * 128 + t];
    }
    Abuf[nid * 128 + t] = a;
    Bbuf[nid * 128 + t] = bb;
}

// ---------- main fused kernel: one block per (b,i) node
__global__ void egnn_main(
    const float* __restrict__ features, const float* __restrict__ coords,
    const float* __restrict__ eW1, const float* __restrict__ eb2,
    const float* __restrict__ eW2,
    const float* __restrict__ nW1, const float* __restrict__ nb1,
    const float* __restrict__ nW2, const float* __restrict__ nb2,
    const float* __restrict__ cW1, const float* __restrict__ cb1,
    const float* __restrict__ cW2, const float* __restrict__ cb2,
    const float* __restrict__ Abuf, const float* __restrict__ Bbuf,
    float* __restrict__ out_feat, float* __restrict__ out_coord)
{
    constexpr int Nn = 512, TJ = 64;
    // se: union buffer. Prologue: stages W^T (128x128 bf16) for fragment loads.
    // Main loop: [0..8191] = s tile (64x128), [8192..16383] = edge_hidden tile.
    __shared__ __align__(16) short se[2 * 64 * 128];
    __shared__ float aw[128], wd[128], eb2s[128], cb1s[128], cw2s[128], fi[128];
    __shared__ float aggb[128], hbuf[128];
    __shared__ float dists[TJ], cdx[TJ], cdy[TJ], cdz[TJ];
    __shared__ float warr4[4][TJ];
    __shared__ float ci3[3];

    const int tid  = threadIdx.x;
    const int lane = tid & 63;
    const int wave = tid >> 6;
    const int node = blockIdx.x;       // == b*512 + i
    const int b    = node >> 9;

    // ---- stage per-node vectors
    if (tid < 128) {
        aw[tid]   = Abuf[node * 128 + tid];      // includes eb1
        wd[tid]   = eW1[256 * 128 + tid];        // distance row of eW1
        eb2s[tid] = eb2[tid];
        cb1s[tid] = cb1[tid];
        cw2s[tid] = cW2[tid];
        fi[tid]   = features[node * 128 + tid];
    }
    if (tid == 0) {
        ci3[0] = coords[node * 3 + 0];
        ci3[1] = coords[node * 3 + 1];
        ci3[2] = coords[node * 3 + 2];
    }

    // ---- stage eW2^T into se (bf16, swizzled), read register B-fragments, repeat for cW1
    short8 wf1[2][4], wf2[2][4];
    {
        const int n = tid & 127, k0 = (tid >> 7) * 64;
        for (int kc = 0; kc < 64; kc += 8) {
            short8 v;
            #pragma unroll
            for (int r = 0; r < 8; ++r) v[r] = f2bf(eW2[(k0 + kc + r) * 128 + n]);
            *(short8*)&se[swz(n, k0 + kc)] = v;
        }
    }
    __syncthreads();
    #pragma unroll
    for (int n2 = 0; n2 < 2; ++n2)
        #pragma unroll
        for (int k = 0; k < 4; ++k)
            wf1[n2][k] = *(const short8*)&se[swz(wave * 32 + n2 * 16 + (lane & 15),
                                                k * 32 + (lane >> 4) * 8)];
    __syncthreads();
    {
        const int n = tid & 127, k0 = (tid >> 7) * 64;
        for (int kc = 0; kc < 64; kc += 8) {
            short8 v;
            #pragma unroll
            for (int r = 0; r < 8; ++r) v[r] = f2bf(cW1[(k0 + kc + r) * 128 + n]);
            *(short8*)&se[swz(n, k0 + kc)] = v;
        }
    }
    __syncthreads();
    #pragma unroll
    for (int n2 = 0; n2 < 2; ++n2)
        #pragma unroll
        for (int k = 0; k < 4; ++k)
            wf2[n2][k] = *(const short8*)&se[swz(wave * 32 + n2 * 16 + (lane & 15),
                                                k * 32 + (lane >> 4) * 8)];
    __syncthreads();

    // per-lane column constants (C-fragment col = n2*16 + wave*32 + (lane&15))
    const int c0l = wave * 32 + (lane & 15);
    const float eb2_0 = eb2s[c0l], eb2_1 = eb2s[c0l + 16];
    const float cb1_0 = cb1s[c0l], cb1_1 = cb1s[c0l + 16];
    const float cw2_0 = cw2s[c0l], cw2_1 = cw2s[c0l + 16];
    const float cb2v  = cb2[0];
    const float cix = ci3[0], ciy = ci3[1], ciz = ci3[2];

    float sagg0 = 0.f, sagg1 = 0.f;          // per-col edge_hidden sums (pre-eb2)
    float cax = 0.f, cay = 0.f, caz = 0.f;   // coord accumulators (wave 0, tid<64)

    for (int j0 = 0; j0 < Nn; j0 += TJ) {
        // -- phase A: distances / coord diffs for this j-tile
        if (tid < TJ) {
            const int j = j0 + tid;
            float dx = cix - coords[(b * Nn + j) * 3 + 0];
            float dy = ciy - coords[(b * Nn + j) * 3 + 1];
            float dz = ciz - coords[(b * Nn + j) * 3 + 2];
            cdx[tid] = dx; cdy[tid] = dy; cdz[tid] = dz;
            dists[tid] = sqrtf(dx * dx + dy * dy + dz * dz + 1e-8f);
        }
        __syncthreads();

        // -- phase s: s = silu(Abuf_i + Bbuf_j + dist*wd) -> bf16 LDS tile
        {
            const int jr = tid >> 2, cb = (tid & 3) * 32;
            const float dj = dists[jr];
            const float* Bj = Bbuf + (size_t)(b * Nn + j0 + jr) * 128 + cb;
            #pragma unroll
            for (int cc = 0; cc < 32; cc += 8) {
                f32x4 x0 = *(const f32x4*)(Bj + cc);
                f32x4 x1 = *(const f32x4*)(Bj + cc + 4);
                short8 v;
                #pragma unroll
                for (int r = 0; r < 4; ++r) {
                    const int c = cb + cc + r;
                    v[r] = f2bf(silu_f(aw[c] + x0[r] + dj * wd[c]));
                }
                #pragma unroll
                for (int r = 0; r < 4; ++r) {
                    const int c = cb + cc + 4 + r;
                    v[4 + r] = f2bf(silu_f(aw[c] + x1[r] + dj * wd[c]));
                }
                *(short8*)&se[swz(jr, cb + cc)] = v;
            }
        }
        __syncthreads();

        // -- GEMM1: edge_hidden = s @ eW2 (per wave: 64 rows x 32-col strip)
        f32x4 acc1[4][2];
        #pragma unroll
        for (int m = 0; m < 4; ++m) { acc1[m][0] = (f32x4)(0.f); acc1[m][1] = (f32x4)(0.f); }
        #pragma unroll
        for (int m = 0; m < 4; ++m)
            #pragma unroll
            for (int k = 0; k < 4; ++k) {
                short8 a = *(const short8*)&se[swz(m * 16 + (lane & 15),
                                                  k * 32 + (lane >> 4) * 8)];
                acc1[m][0] = MFMA16(a, wf1[0][k], acc1[m][0]);
                acc1[m][1] = MFMA16(a, wf1[1][k], acc1[m][1]);
            }

        // -- write edge_hidden(+eb2) bf16 to LDS; accumulate j-sum for aggregation
        #pragma unroll
        for (int m = 0; m < 4; ++m)
            #pragma unroll
            for (int reg = 0; reg < 4; ++reg) {
                const int row = m * 16 + (lane >> 4) * 4 + reg;
                const float e0 = acc1[m][0][reg], e1 = acc1[m][1][reg];
                sagg0 += e0; sagg1 += e1;
                se[8192 + swz(row, c0l)]      = f2bf(e0 + eb2_0);
                se[8192 + swz(row, c0l + 16)] = f2bf(e1 + eb2_1);
            }
        __syncthreads();

        // -- GEMM2: c1 = edge_hidden @ cW1
        f32x4 acc2[4][2];
        #pragma unroll
        for (int m = 0; m < 4; ++m) { acc2[m][0] = (f32x4)(0.f); acc2[m][1] = (f32x4)(0.f); }
        #pragma unroll
        for (int m = 0; m < 4; ++m)
            #pragma unroll
            for (int k = 0; k < 4; ++k) {
                short8 a = *(const short8*)&se[8192 + swz(m * 16 + (lane & 15),
                                                          k * 32 + (lane >> 4) * 8)];
                acc2[m][0] = MFMA16(a, wf2[0][k], acc2[m][0]);
                acc2[m][1] = MFMA16(a, wf2[1][k], acc2[m][1]);
            }

        // -- coord weights: w[j] = silu(c1) . cW2 + cb2 ; butterfly over lane&15
        #pragma unroll
        for (int m = 0; m < 4; ++m)
            #pragma unroll
            for (int reg = 0; reg < 4; ++reg) {
                float v = silu_f(acc2[m][0][reg] + cb1_0) * cw2_0
                        + silu_f(acc2[m][1][reg] + cb1_1) * cw2_1;
                v += __shfl_xor(v, 1); v += __shfl_xor(v, 2);
                v += __shfl_xor(v, 4); v += __shfl_xor(v, 8);
                if ((lane & 15) == 0)
                    warr4[wave][m * 16 + (lane >> 4) * 4 + reg] = v;
            }
        __syncthreads();

        // -- coord accumulation (wave 0)
        if (tid < TJ) {
            const float w = warr4[0][tid] + warr4[1][tid] + warr4[2][tid] + warr4[3][tid] + cb2v;
            cax += w * cdx[tid]; cay += w * cdy[tid]; caz += w * cdz[tid];
        }
        __syncthreads();
    }

    // ---- aggregated = mean_j(edge_hidden) = sum/512 + eb2
    {
        float v0 = sagg0; v0 += __shfl_xor(v0, 16); v0 += __shfl_xor(v0, 32);
        float v1 = sagg1; v1 += __shfl_xor(v1, 16); v1 += __shfl_xor(v1, 32);
        if (lane < 16) {
            aggb[wave * 32 + lane]      = v0 * (1.f / 512.f) + eb2s[wave * 32 + lane];
            aggb[wave * 32 + 16 + lane] = v1 * (1.f / 512.f) + eb2s[wave * 32 + 16 + lane];
        }
    }
    // ---- coords out
    if (tid < 64) {
        float sx = cax, sy = cay, sz = caz;
        #pragma unroll
        for (int o = 1; o < 64; o <<= 1) {
            sx += __shfl_xor(sx, o); sy += __shfl_xor(sy, o); sz += __shfl_xor(sz, o);
        }
        if (tid == 0) {
            out_coord[node * 3 + 0] = cix + sx * (1.f / 512.f);
            out_coord[node * 3 + 1] = ciy + sy * (1.f / 512.f);
            out_coord[node * 3 + 2] = ciz + sz * (1.f / 512.f);
        }
    }
    __syncthreads();

    // ---- node MLP: out = silu([feat_i, agg] @ nW1 + nb1) @ nW2 + nb2  (scalar f32, tiny)
    if (tid < 128) {
        float acc = nb1[tid];
        #pragma unroll 4
        for (int k = 0; k < 128; ++k) acc += fi[k] * nW1[k * 128 + tid];
        #pragma unroll 4
        for (int k = 0; k < 128; ++k) acc += aggb[k] * nW1[(128 + k) * 128 + tid];
        hbuf[tid] = silu_f(acc);
    }
    __syncthreads();
    if (tid < 128) {
        float acc = nb2[tid];
        #pragma unroll 4
        for (int k = 0; k < 128; ++k) acc += hbuf[k] * nW2[k * 128 + tid];
        out_feat[node * 128 + tid] = acc;
    }
}

extern "C" void kernel_launch(void* const* d_in, const int* in_sizes, int n_in,
                              void* d_out, int out_size, void* d_ws, size_t ws_size,
                              hipStream_t stream)
{
    const float* features = (const float*)d_in[0];
    const float* coords   = (const float*)d_in[1];
    const float* eW1 = (const float*)d_in[2];
    const float* eb1 = (const float*)d_in[3];
    const float* eW2 = (const float*)d_in[4];
    const float* eb2 = (const float*)d_in[5];
    const float* nW1 = (const float*)d_in[6];
    const float* nb1 = (const float*)d_in[7];
    const float* nW2 = (const float*)d_in[8];
    const float* nb2 = (const float*)d_in[9];
    const float* cW1 = (const float*)d_in[10];
    const float* cb1 = (const float*)d_in[11];
    const float* cW2 = (const float*)d_in[12];
    const float* cb2 = (const float*)d_in[13];

    float* out = (float*)d_out;
    float* out_feat  = out;                       // (2,512,128)
    float* out_coord = out + 2 * 512 * 128;       // (2,512,3)

    float* Abuf = (float*)d_ws;                   // 2*512*128 f32
    float* Bbuf = Abuf + 2 * 512 * 128;           // 2*512*128 f32

    egnn_pre<<<1024, 128, 0, stream>>>(features, eW1, eb1, Abuf, Bbuf);
    egnn_main<<<1024, 256, 0, stream>>>(features, coords, eW1, eb2, eW2,
                                        nW1, nb1, nW2, nb2, cW1, cb1, cW2, cb2,
                                        Abuf, Bbuf, out_feat, out_coord);
}